// Round 10
// baseline (77.321 us; speedup 1.0000x reference)
//
#include <hip/hip_runtime.h>
#include <math.h>

#define NCOL 8192
#define NROW 4096
#define KSEL 819
#define TPB  256
#define VPT  8            // f32x4 per thread = 32 elements
#define NBKT 1024
#define PIV  1.05f        // survivor pivot: E[C]~1200 >> 819 (12 sigma)
#define BSCALE 512.0f     // bucket width 1/512 over v in [1.05, 3.05]
#define LCAP 64

typedef float f32x4 __attribute__((ext_vector_type(4)));

// Per-column boost factors, recomputed every launch (deterministic).
__device__ __align__(16) float g_boost[NCOL];

__global__ void boost_kernel(const float* __restrict__ duty) {
    int i = blockIdx.x * blockDim.x + threadIdx.x;
    if (i < NCOL) {
        // target_density = 819/8192 exactly; boost_strength = 1
        float diff = (0.0999755859375f - duty[i]);
        g_boost[i] = (float)exp((double)diff);   // correctly-rounded f32 exp (matches np)
    }
}

__device__ __forceinline__ unsigned f2k(float f) {
    unsigned u = __float_as_uint(f);
    return u ^ (0x80000000u | (unsigned)((int)u >> 31));
}
__device__ __forceinline__ float k2f(unsigned k) {
    unsigned u = (k & 0x80000000u) ? (k ^ 0x80000000u) : ~k;
    return __uint_as_float(u);
}
__device__ __forceinline__ int vbucket(float v) {
    int b = (int)((v - PIV) * BSCALE);          // monotone for v > PIV
    b = (b < 0) ? 0 : b;
    return (b > NBKT - 1) ? (NBKT - 1) : b;
}

// ---------------- Kernel 1: per-row threshold (read x once, no row write) ----------------
__global__ __launch_bounds__(TPB) void thresh_kernel(const float* __restrict__ x,
                                                     float* __restrict__ thf,
                                                     int* __restrict__ rfo,
                                                     int* __restrict__ eo) {
    __shared__ __align__(16) int hist[NBKT];    // 4 KB; fallback uses bins [0,256)
    __shared__ float list[LCAP];
    __shared__ int wtot[4];
    __shared__ int lds_cnt, lds_sel, lds_R, lds_E;

    const int t = threadIdx.x, lane = t & 63, w = t >> 6;
    const int row = blockIdx.x;
    const f32x4* x4 = (const f32x4*)(x + (size_t)row * NCOL);
    const f32x4* b4 = (const f32x4*)g_boost;

    f32x4 vv[VPT];                              // boosted values — the only row state

    ((int4*)hist)[t] = make_int4(0, 0, 0, 0);   // 1024 ints by 256 threads
    if (t == 0) lds_cnt = 0;

    // x loads are REGULAR (not nontemporal): warms L3 for apply_kernel
#pragma unroll
    for (int j = 0; j < VPT; ++j) {
        f32x4 xx = x4[t + TPB * j];
        f32x4 bb = b4[t + TPB * j];
        vv[j].x = xx.x * bb.x; vv[j].y = xx.y * bb.y;
        vv[j].z = xx.z * bb.z; vv[j].w = xx.w * bb.w;
    }
    __syncthreads();                            // sync1: zeros visible

    // survivor histogram + survivor count
    int cnt = 0;
#pragma unroll
    for (int j = 0; j < VPT; ++j) {
#pragma unroll
        for (int c = 0; c < 4; ++c) {
            float v = vv[j][c];
            if (v > PIV) { ++cnt; atomicAdd(&hist[vbucket(v)], 1); }
        }
    }
#pragma unroll
    for (int off = 32; off; off >>= 1) cnt += __shfl_down(cnt, off);
    if (lane == 0) wtot[w] = cnt;
    __syncthreads();                            // sync2: hist + wtot complete

    const int C = wtot[0] + wtot[1] + wtot[2] + wtot[3];
    float th = 0.0f; int Rf = 0, E = 0;
    bool fb = (C < KSEL);

    if (!fb) {
        // redundant per-wave suffix scan of 1024 bins (16/lane) — no writeback, no sync
        int arr[16];
        {
            int4 a0 = ((const int4*)hist)[4 * lane + 0];
            int4 a1 = ((const int4*)hist)[4 * lane + 1];
            int4 a2 = ((const int4*)hist)[4 * lane + 2];
            int4 a3 = ((const int4*)hist)[4 * lane + 3];
            arr[0]=a0.x; arr[1]=a0.y; arr[2]=a0.z; arr[3]=a0.w;
            arr[4]=a1.x; arr[5]=a1.y; arr[6]=a1.z; arr[7]=a1.w;
            arr[8]=a2.x; arr[9]=a2.y; arr[10]=a2.z; arr[11]=a2.w;
            arr[12]=a3.x; arr[13]=a3.y; arr[14]=a3.z; arr[15]=a3.w;
        }
        int ts = 0;
#pragma unroll
        for (int b = 0; b < 16; ++b) ts += arr[b];
        int s = ts;
#pragma unroll
        for (int off = 1; off < 64; off <<= 1) {
            int o = __shfl_down(s, off);
            if (lane + off < 64) s += o;
        }
        const int S_ab = s - ts;
        bool cross = (S_ab < KSEL) && (S_ab + ts >= KSEL);
        int sel_l = 0, r1_l = 0;
        if (cross) {
            int cum = S_ab;
#pragma unroll
            for (int b = 15; b >= 0; --b) {
                int nx = cum + arr[b];
                if (cum < KSEL && nx >= KSEL) { sel_l = 16 * lane + b; r1_l = KSEL - cum; }
                cum = nx;
            }
        }
        unsigned long long m = __ballot(cross); // exactly one lane per wave
        int src = (int)__ffsll(m) - 1;
        const int sel = __shfl(sel_l, src);
        const int R1  = __shfl(r1_l, src);

        // gather selected bucket's values
#pragma unroll
        for (int j = 0; j < VPT; ++j)
#pragma unroll
            for (int c = 0; c < 4; ++c) {
                float v = vv[j][c];
                if (v > PIV && vbucket(v) == sel) {
                    int sl = atomicAdd(&lds_cnt, 1);
                    if (sl < LCAP) list[sl] = v;
                }
            }
        __syncthreads();                        // sync3: list complete
        const int n = lds_cnt;
        if (n > LCAP || n < 1) fb = true;
        else {
            // redundant per-wave exact rank-select on the tiny list (n <= 64)
            float myv = (lane < n) ? list[lane] : 0.0f;
            int g = 0, e = 0;
            for (int i = 0; i < n; ++i) {
                float vi = __shfl(myv, i);
                g += (vi > myv) ? 1 : 0;
                e += (vi == myv) ? 1 : 0;
            }
            float cand = (lane < n && g < R1 && g + e >= R1) ? myv : 0.0f;
#pragma unroll
            for (int off = 1; off < 64; off <<= 1)
                cand = fmaxf(cand, __shfl_xor(cand, off));
            th = cand;

            // certify from registers: G = #{v>th}, E = #{v==th}, packed
            int GE = 0;
#pragma unroll
            for (int j = 0; j < VPT; ++j)
#pragma unroll
                for (int c = 0; c < 4; ++c) {
                    float v = vv[j][c];
                    GE += (v > th ? 1 : 0) + (v == th ? (1 << 16) : 0);
                }
#pragma unroll
            for (int off = 1; off < 64; off <<= 1) GE += __shfl_xor(GE, off);
            if (lane == 0) wtot[w] = GE;
            __syncthreads();                    // sync4
            const int GEt = wtot[0] + wtot[1] + wtot[2] + wtot[3];
            const int G = GEt & 0xFFFF, Eg = GEt >> 16;
            if (G < KSEL && G + Eg >= KSEL) { Rf = KSEL - G; E = Eg; }
            else fb = true;                     // certification failed
        }
    }

    if (fb) {   // guaranteed 4x8-bit key radix select (rare) — R6-proven structure
        unsigned prefix = 0; int R = KSEL;
        for (int p = 0; p < 4; ++p) {
            const int sh = 24 - 8 * p;
            hist[t] = 0;
            __syncthreads();
#pragma unroll
            for (int j = 0; j < VPT; ++j)
#pragma unroll
                for (int c = 0; c < 4; ++c) {
                    unsigned k = f2k(vv[j][c]);
                    if (p == 0 || (k >> (sh + 8)) == (prefix >> (sh + 8)))
                        atomicAdd(&hist[(k >> sh) & 255u], 1);
                }
            __syncthreads();
            int h = hist[t], s2 = h;
#pragma unroll
            for (int off = 1; off < 64; off <<= 1) {
                int o = __shfl_down(s2, off);
                if (lane + off < 64) s2 += o;
            }
            if (lane == 0) wtot[w] = s2;
            __syncthreads();
            int S_later = 0;
#pragma unroll
            for (int w2 = 0; w2 < 4; ++w2) if (w2 > w) S_later += wtot[w2];
            const int S_ab2 = (s2 - h) + S_later;
            if (S_ab2 < R && S_ab2 + h >= R) { lds_sel = t; lds_R = R - S_ab2; lds_E = h; }
            __syncthreads();
            prefix |= ((unsigned)lds_sel) << sh;
            R = lds_R;
        }
        th = k2f(prefix); Rf = R; E = lds_E;
    }

    if (t == 0) { thf[row] = th; rfo[row] = Rf; eo[row] = E; }
}

// ---------------- Kernel 2: apply (pure stream, zero barriers on hot path) ----------------
__global__ __launch_bounds__(TPB) void apply_kernel(const float* __restrict__ x,
                                                    const float* __restrict__ thf,
                                                    const int* __restrict__ rfo,
                                                    const int* __restrict__ eo,
                                                    float* __restrict__ out) {
    __shared__ unsigned short tl[2048];
    __shared__ int lds_cnt;

    const int t = threadIdx.x;
    const int row = blockIdx.x;
    const f32x4* x4 = (const f32x4*)(x + (size_t)row * NCOL);
    const f32x4* b4 = (const f32x4*)g_boost;
    f32x4* o4 = (f32x4*)(out + (size_t)row * NCOL);

    const float th = thf[row];
    const int Rf = rfo[row], E = eo[row];

    // x read (L3-hot from thresh_kernel); out nontemporal (no-allocate, protects x in L3)
#pragma unroll
    for (int j = 0; j < VPT; ++j) {
        f32x4 xx = x4[t + TPB * j];
        f32x4 bb = b4[t + TPB * j];
        f32x4 rr;
        rr.x = (xx.x * bb.x >= th) ? xx.x : 0.0f;
        rr.y = (xx.y * bb.y >= th) ? xx.y : 0.0f;
        rr.z = (xx.z * bb.z >= th) ? xx.z : 0.0f;
        rr.w = (xx.w * bb.w >= th) ? xx.w : 0.0f;
        __builtin_nontemporal_store(rr, &o4[t + TPB * j]);
    }

    if (E > Rf) {   // tie demotion (lax.top_k keeps lowest columns) — essentially never
        asm volatile("s_waitcnt vmcnt(0)" ::: "memory");
        __syncthreads();
        if (t == 0) lds_cnt = 0;
        __syncthreads();
#pragma unroll
        for (int j = 0; j < VPT; ++j) {
            f32x4 xx = x4[t + TPB * j];
            f32x4 bb = b4[t + TPB * j];
#pragma unroll
            for (int c = 0; c < 4; ++c) {
                float v = xx[c] * bb[c];
                if (v == th) {
                    int sl = atomicAdd(&lds_cnt, 1);
                    if (sl < 2048) tl[sl] = (unsigned short)(4 * (t + TPB * j) + c);
                }
            }
        }
        __syncthreads();
        const int ntie = lds_cnt;
        float* orow = out + (size_t)row * NCOL;
        if (ntie <= 2048) {
#pragma unroll
            for (int j = 0; j < VPT; ++j) {
                f32x4 xx = x4[t + TPB * j];
                f32x4 bb = b4[t + TPB * j];
#pragma unroll
                for (int c = 0; c < 4; ++c) {
                    float v = xx[c] * bb[c];
                    if (v == th) {
                        const int col = 4 * (t + TPB * j) + c;
                        int rk = 0;
                        for (int i = 0; i < ntie; ++i) rk += (tl[i] < col) ? 1 : 0;
                        if (rk >= Rf) orow[col] = 0.0f;
                    }
                }
            }
        } else if (t == 0) {   // >2048 identical values: never on real data, but correct
            int seen = 0;
            for (int col = 0; col < NCOL; ++col) {
                float v = x[(size_t)row * NCOL + col] * g_boost[col];
                if (v == th) { if (seen >= Rf) orow[col] = 0.0f; ++seen; }
            }
        }
    }
}

extern "C" void kernel_launch(void* const* d_in, const int* in_sizes, int n_in,
                              void* d_out, int out_size, void* d_ws, size_t ws_size,
                              hipStream_t stream) {
    const float* x = (const float*)d_in[0];        // [4096, 8192] f32
    const float* duty = (const float*)d_in[1];     // [8192] f32
    float* out = (float*)d_out;                    // [4096, 8192] f32
    (void)in_sizes; (void)n_in; (void)out_size; (void)ws_size;

    float* thf = (float*)d_ws;                     // [NROW] threshold (float value)
    int*   rfo = (int*)d_ws + NROW;                // [NROW] # equal-to-th to keep
    int*   eo  = (int*)d_ws + 2 * NROW;            // [NROW] # equal-to-th total

    boost_kernel<<<(NCOL + 255) / 256, 256, 0, stream>>>(duty);
    thresh_kernel<<<NROW, TPB, 0, stream>>>(x, thf, rfo, eo);
    apply_kernel<<<NROW, TPB, 0, stream>>>(x, thf, rfo, eo, out);
}

// Round 11
// 75.601 us; speedup vs baseline: 1.0228x; 1.0228x over previous
//
#include <hip/hip_runtime.h>
#include <math.h>

#define NCOL 8192
#define NROW 4096
#define KSEL 819
#define TPB  256
#define VPT  8            // f32x4 per thread = 32 elements
#define ROWS 8            // rows per persistent block; grid = 512 = 2 blocks/CU
#define NBKT 1024
#define PIV  1.05f        // survivor pivot: E[C]~1200 >> 819
#define BSCALE 512.0f
#define LCAP 64

typedef float f32x4 __attribute__((ext_vector_type(4)));

// Per-column boost factors, recomputed every launch (deterministic).
__device__ __align__(16) float g_boost[NCOL];

__global__ void boost_kernel(const float* __restrict__ duty) {
    int i = blockIdx.x * blockDim.x + threadIdx.x;
    if (i < NCOL) {
        // target_density = 819/8192 exactly; boost_strength = 1
        float diff = (0.0999755859375f - duty[i]);
        g_boost[i] = (float)exp((double)diff);   // correctly-rounded f32 exp (matches np)
    }
}

__device__ __forceinline__ unsigned f2k(float f) {
    unsigned u = __float_as_uint(f);
    return u ^ (0x80000000u | (unsigned)((int)u >> 31));
}
__device__ __forceinline__ float k2f(unsigned k) {
    unsigned u = (k & 0x80000000u) ? (k ^ 0x80000000u) : ~k;
    return __uint_as_float(u);
}
__device__ __forceinline__ int vbucket(float v) {
    int b = (int)((v - PIV) * BSCALE);          // monotone for v > PIV
    b = (b < 0) ? 0 : b;
    return (b > NBKT - 1) ? (NBKT - 1) : b;
}

#define LGKM0() do { asm volatile("s_waitcnt lgkmcnt(0)" ::: "memory"); \
                     __builtin_amdgcn_sched_barrier(0); } while (0)
#define VM0()   do { asm volatile("s_waitcnt vmcnt(0)" ::: "memory"); \
                     __builtin_amdgcn_sched_barrier(0); } while (0)
#define BAR()   __builtin_amdgcn_s_barrier()

__global__ __launch_bounds__(TPB) void kwinners_kernel(const float* __restrict__ x,
                                                       float* __restrict__ out) {
    __shared__ __align__(16) float xb[2][NCOL];   // 64 KB double buffer (DMA-staged)
    __shared__ __align__(16) int hist[NBKT];      // 4 KB; fallback bins / tie list
    __shared__ float list[LCAP];
    __shared__ int wtot[4];
    __shared__ int scal[4];                       // [0]=cnt [1]=sel [2]=R [3]=E

    const int t = threadIdx.x, lane = t & 63, w = t >> 6;
    const int row0 = blockIdx.x * ROWS;

    // boost -> registers once (row-invariant: thread t always owns the same 32 cols)
    f32x4 bb[VPT];
#pragma unroll
    for (int j = 0; j < VPT; ++j) bb[j] = ((const f32x4*)g_boost)[t + TPB * j];

    // async-stage a row into xb[b]: per wave, 8 x (64 lanes x 16B) = 8 KB section
#define STAGE(b, rw) do {                                                         \
        const float* gs_ = x + (size_t)(rw) * NCOL + (w << 11) + (lane << 2);     \
        _Pragma("unroll")                                                         \
        for (int i_ = 0; i_ < 8; ++i_)                                            \
            __builtin_amdgcn_global_load_lds(                                     \
                (const __attribute__((address_space(1))) unsigned*)(gs_ + (i_ << 8)), \
                (__attribute__((address_space(3))) unsigned*)(&xb[b][(w << 11) + (i_ << 8)]), \
                16, 0, 0);                                                        \
    } while (0)

    STAGE(0, row0);                               // prologue

    for (int r = 0; r < ROWS; ++r) {
        const int row = row0 + r, cur = r & 1;

        VM0();                                    // cur buf staged; old stores drained
        ((int4*)hist)[t] = make_int4(0, 0, 0, 0); // zero 1024 bins
        if (t == 0) scal[0] = 0;
        LGKM0();
        BAR();                                    // raw barrier: buf + zeros visible

        if (r + 1 < ROWS) STAGE(cur ^ 1, row + 1);   // prefetch flies over select+write

        // boosted values -> regs; survivor histogram
        f32x4 vv[VPT];
        int cnt = 0;
#pragma unroll
        for (int j = 0; j < VPT; ++j) {
            f32x4 xx = *(const f32x4*)&xb[cur][4 * (t + TPB * j)];
            vv[j] = xx * bb[j];
#pragma unroll
            for (int c = 0; c < 4; ++c) {
                float v = vv[j][c];
                if (v > PIV) { ++cnt; atomicAdd(&hist[vbucket(v)], 1); }
            }
        }
#pragma unroll
        for (int off = 32; off; off >>= 1) cnt += __shfl_down(cnt, off);
        if (lane == 0) wtot[w] = cnt;
        LGKM0();
        BAR();                                    // hist + counts final
        const int C = wtot[0] + wtot[1] + wtot[2] + wtot[3];

        float th = 0.0f; int Rf = 0, E = 0;
        bool fb = (C < KSEL);

        if (!fb) {
            // redundant per-wave suffix scan of 1024 bins (16/lane)
            int arr[16];
            {
                int4 a0 = ((const int4*)hist)[4 * lane + 0];
                int4 a1 = ((const int4*)hist)[4 * lane + 1];
                int4 a2 = ((const int4*)hist)[4 * lane + 2];
                int4 a3 = ((const int4*)hist)[4 * lane + 3];
                arr[0]=a0.x; arr[1]=a0.y; arr[2]=a0.z; arr[3]=a0.w;
                arr[4]=a1.x; arr[5]=a1.y; arr[6]=a1.z; arr[7]=a1.w;
                arr[8]=a2.x; arr[9]=a2.y; arr[10]=a2.z; arr[11]=a2.w;
                arr[12]=a3.x; arr[13]=a3.y; arr[14]=a3.z; arr[15]=a3.w;
            }
            int ts = 0;
#pragma unroll
            for (int b = 0; b < 16; ++b) ts += arr[b];
            int s = ts;
#pragma unroll
            for (int off = 1; off < 64; off <<= 1) {
                int o = __shfl_down(s, off);
                if (lane + off < 64) s += o;
            }
            const int S_ab = s - ts;
            bool cross = (S_ab < KSEL) && (S_ab + ts >= KSEL);
            int sel_l = 0, r1_l = 0;
            if (cross) {
                int cum = S_ab;
#pragma unroll
                for (int b = 15; b >= 0; --b) {
                    int nx = cum + arr[b];
                    if (cum < KSEL && nx >= KSEL) { sel_l = 16 * lane + b; r1_l = KSEL - cum; }
                    cum = nx;
                }
            }
            unsigned long long m = __ballot(cross);
            int src = (int)__ffsll(m) - 1;
            const int sel = __shfl(sel_l, src);
            const int R1  = __shfl(r1_l, src);

            // gather selected bucket's values
#pragma unroll
            for (int j = 0; j < VPT; ++j)
#pragma unroll
                for (int c = 0; c < 4; ++c) {
                    float v = vv[j][c];
                    if (v > PIV && vbucket(v) == sel) {
                        int sl = atomicAdd(&scal[0], 1);
                        if (sl < LCAP) list[sl] = v;
                    }
                }
            LGKM0();
            BAR();                                // list final
            const int n = scal[0];
            if (n > LCAP || n < 1) fb = true;
            else {
                float myv = (lane < n) ? list[lane] : 0.0f;
                int g = 0, e = 0;
                for (int i = 0; i < n; ++i) {
                    float vi = __shfl(myv, i);
                    g += (vi > myv) ? 1 : 0;
                    e += (vi == myv) ? 1 : 0;
                }
                float cand = (lane < n && g < R1 && g + e >= R1) ? myv : 0.0f;
#pragma unroll
                for (int off = 1; off < 64; off <<= 1)
                    cand = fmaxf(cand, __shfl_xor(cand, off));
                th = cand;

                // certify from registers: G = #{v>th}, E = #{v==th}
                int GE = 0;
#pragma unroll
                for (int j = 0; j < VPT; ++j)
#pragma unroll
                    for (int c = 0; c < 4; ++c) {
                        float v = vv[j][c];
                        GE += (v > th ? 1 : 0) + (v == th ? (1 << 16) : 0);
                    }
#pragma unroll
                for (int off = 1; off < 64; off <<= 1) GE += __shfl_xor(GE, off);
                if (lane == 0) wtot[w] = GE;
                LGKM0();
                BAR();                            // GE combine
                const int GEt = wtot[0] + wtot[1] + wtot[2] + wtot[3];
                const int G = GEt & 0xFFFF, Eg = GEt >> 16;
                if (G < KSEL && G + Eg >= KSEL) { Rf = KSEL - G; E = Eg; }
                else fb = true;
            }
        }

        if (fb) {   // guaranteed 4x8-bit key radix select (rare, block-uniform)
            unsigned prefix = 0; int R = KSEL;
            for (int p = 0; p < 4; ++p) {
                const int sh = 24 - 8 * p;
                if (t < 64) ((int4*)hist)[t] = make_int4(0, 0, 0, 0);   // 256 bins
                LGKM0(); BAR();
#pragma unroll
                for (int j = 0; j < VPT; ++j)
#pragma unroll
                    for (int c = 0; c < 4; ++c) {
                        unsigned k = f2k(vv[j][c]);
                        if (p == 0 || (k >> (sh + 8)) == (prefix >> (sh + 8)))
                            atomicAdd(&hist[(k >> sh) & 255u], 1);
                    }
                LGKM0(); BAR();
                int h = hist[t], s2 = h;
#pragma unroll
                for (int off = 1; off < 64; off <<= 1) {
                    int o = __shfl_down(s2, off);
                    if (lane + off < 64) s2 += o;
                }
                if (lane == 0) wtot[w] = s2;
                LGKM0(); BAR();
                int S_later = 0;
#pragma unroll
                for (int w2 = 0; w2 < 4; ++w2) if (w2 > w) S_later += wtot[w2];
                const int S_ab2 = (s2 - h) + S_later;
                if (S_ab2 < R && S_ab2 + h >= R) { scal[1] = t; scal[2] = R - S_ab2; scal[3] = h; }
                LGKM0(); BAR();
                prefix |= ((unsigned)scal[1]) << sh;
                R = scal[2];
            }
            th = k2f(prefix); Rf = R; E = scal[3];
        }

        // write: original x from LDS at winners, 0 elsewhere
        f32x4* o4 = (f32x4*)(out + (size_t)row * NCOL);
#pragma unroll
        for (int j = 0; j < VPT; ++j) {
            f32x4 xx = *(const f32x4*)&xb[cur][4 * (t + TPB * j)];
            f32x4 rr;
            rr.x = (vv[j].x >= th) ? xx.x : 0.0f;
            rr.y = (vv[j].y >= th) ? xx.y : 0.0f;
            rr.z = (vv[j].z >= th) ? xx.z : 0.0f;
            rr.w = (vv[j].w >= th) ? xx.w : 0.0f;
            __builtin_nontemporal_store(rr, &o4[t + TPB * j]);
        }

        if (E > Rf) {   // tie demotion (lax.top_k keeps lowest columns) — rare
            VM0();                                 // row writes drained before patching
            BAR();
            unsigned short* tl = (unsigned short*)hist;   // cap 2048 cols
            if (t == 0) scal[0] = 0;
            LGKM0(); BAR();
#pragma unroll
            for (int j = 0; j < VPT; ++j)
#pragma unroll
                for (int c = 0; c < 4; ++c)
                    if (vv[j][c] == th) {
                        int sl = atomicAdd(&scal[0], 1);
                        if (sl < 2048) tl[sl] = (unsigned short)(4 * (t + TPB * j) + c);
                    }
            LGKM0(); BAR();
            const int ntie = scal[0];
            float* orow = out + (size_t)row * NCOL;
            if (ntie <= 2048) {
#pragma unroll
                for (int j = 0; j < VPT; ++j)
#pragma unroll
                    for (int c = 0; c < 4; ++c)
                        if (vv[j][c] == th) {
                            const int col = 4 * (t + TPB * j) + c;
                            int rk = 0;
                            for (int i = 0; i < ntie; ++i) rk += (tl[i] < col) ? 1 : 0;
                            if (rk >= Rf) orow[col] = 0.0f;
                        }
            } else if (t == 0) {   // >2048 identical values: never on real data
                int seen = 0;
                for (int col = 0; col < NCOL; ++col) {
                    float v = xb[cur][col] * g_boost[col];
                    if (v == th) { if (seen >= Rf) orow[col] = 0.0f; ++seen; }
                }
            }
        }

        BAR();   // end-of-row rendezvous: hist/list/wtot/xb safe to reuse
    }
}

extern "C" void kernel_launch(void* const* d_in, const int* in_sizes, int n_in,
                              void* d_out, int out_size, void* d_ws, size_t ws_size,
                              hipStream_t stream) {
    const float* x = (const float*)d_in[0];        // [4096, 8192] f32
    const float* duty = (const float*)d_in[1];     // [8192] f32
    float* out = (float*)d_out;                    // [4096, 8192] f32
    (void)in_sizes; (void)n_in; (void)out_size; (void)d_ws; (void)ws_size;

    boost_kernel<<<(NCOL + 255) / 256, 256, 0, stream>>>(duty);
    kwinners_kernel<<<NROW / ROWS, TPB, 0, stream>>>(x, out);
}

// Round 12
// 70.803 us; speedup vs baseline: 1.0921x; 1.0678x over previous
//
#include <hip/hip_runtime.h>
#include <math.h>

#define NCOL 8192
#define NROW 4096
#define KSEL 819
#define TPB  256
#define VPT  8            // f32x4 per thread = 32 elements
#define RPB  2            // rows per block; grid = 2048 = exactly 8 blocks/CU
#define LCAP 256          // candidate-list capacity (expected n ~ 1-3)
#define KPIV 0xBF866666u  // f2k(1.05f): survivor pivot in KEY space
#define NBKT 2048

typedef float f32x4 __attribute__((ext_vector_type(4)));

// Per-column boost factors, recomputed every launch (deterministic).
__device__ __align__(16) float g_boost[NCOL];

__global__ void boost_kernel(const float* __restrict__ duty) {
    int i = blockIdx.x * blockDim.x + threadIdx.x;
    if (i < NCOL) {
        // target_density = 819/8192 exactly; boost_strength = 1
        float diff = (0.0999755859375f - duty[i]);
        g_boost[i] = (float)exp((double)diff);   // correctly-rounded f32 exp (matches np)
    }
}

__device__ __forceinline__ unsigned f2k(float f) {
    // monotone float -> uint map (total order)
    unsigned u = __float_as_uint(f);
    return u ^ (0x80000000u | (unsigned)((int)u >> 31));
}

__device__ __forceinline__ int kbucket(unsigned k) {
    // pure-integer monotone bucket of the key; survivors (k>KPIV) -> [0, 2047]
    int b = (int)(k >> 13) - (int)(KPIV >> 13);
    return (b > NBKT - 1) ? (NBKT - 1) : b;
}

__global__ __launch_bounds__(TPB) void kwinners_kernel(const float* __restrict__ x,
                                                       float* __restrict__ out) {
    // smem: [0,8KB) 2048-bucket hist / fallback 256-bin hist / tie list (ushort, 16KB)
    //       [8KB,9KB) lkey[256]
    __shared__ __align__(16) unsigned char smem[16384];
    __shared__ int lds_wtot[4];
    __shared__ int lds_C, lds_cnt, lds_sel, lds_R1, lds_fE, lds_fR;
    __shared__ unsigned lds_th;

    int* hist = (int*)smem;
    unsigned* lkey = (unsigned*)(smem + 8192);

    const int t = threadIdx.x, lane = t & 63, w = t >> 6;
    const f32x4* b4 = (const f32x4*)g_boost;

    // ---- de-convoy stagger: one-time pseudo-random phase offset (0..2.8us) ----
    {
        const unsigned ph = ((unsigned)blockIdx.x * 2654435761u) >> 29;   // 0..7
        if (ph) {
            long long t0 = wall_clock64();                 // 100 MHz ref clock
            const long long tgt = (long long)ph * 40;      // 0.4us steps
            while (wall_clock64() - t0 < tgt) __builtin_amdgcn_s_sleep(8);
        }
    }

    for (int r = 0; r < RPB; ++r) {
        const int row = blockIdx.x * RPB + r;
        const f32x4* x4 = (const f32x4*)(x + (size_t)row * NCOL);

        unsigned kr[VPT][4];

        // zero bucket hist + scalars
        {
            int4* h4 = (int4*)hist;
            const int4 z = make_int4(0, 0, 0, 0);
            h4[2 * t] = z; h4[2 * t + 1] = z;
            if (t == 0) { lds_C = 0; lds_cnt = 0; lds_th = 0xFFFFFFFFu; }
        }

        // load x + boost, keys -> registers (kept for all later phases)
#pragma unroll
        for (int j = 0; j < VPT; ++j) {
            f32x4 xx = x4[t + TPB * j];
            f32x4 bb = b4[t + TPB * j];
            kr[j][0] = f2k(xx.x * bb.x);
            kr[j][1] = f2k(xx.y * bb.y);
            kr[j][2] = f2k(xx.z * bb.z);
            kr[j][3] = f2k(xx.w * bb.w);
        }
        __syncthreads();

        // survivor count + sparse key-bucket histogram (survivors only)
        int cnt = 0;
#pragma unroll
        for (int j = 0; j < VPT; ++j)
#pragma unroll
            for (int c = 0; c < 4; ++c) {
                unsigned k = kr[j][c];
                if (k > KPIV) { ++cnt; atomicAdd(&hist[kbucket(k)], 1); }
            }
#pragma unroll
        for (int off = 32; off; off >>= 1) cnt += __shfl_down(cnt, off);
        if (lane == 0) atomicAdd(&lds_C, cnt);
        __syncthreads();
        const int C = lds_C;

        unsigned th = 0; int Rf = 0, E = 0; bool ok = false;

        if (C >= KSEL) {
            // one suffix-scan of 2048 buckets (8/thread) -> selected bucket + rank
            int arr[8];
            {
                int4 a0 = ((const int4*)hist)[2 * t];
                int4 a1 = ((const int4*)hist)[2 * t + 1];
                arr[0] = a0.x; arr[1] = a0.y; arr[2] = a0.z; arr[3] = a0.w;
                arr[4] = a1.x; arr[5] = a1.y; arr[6] = a1.z; arr[7] = a1.w;
            }
            int ts = arr[0] + arr[1] + arr[2] + arr[3] + arr[4] + arr[5] + arr[6] + arr[7];
            int s = ts;
#pragma unroll
            for (int off = 1; off < 64; off <<= 1) {
                int o = __shfl_down(s, off);
                if (lane + off < 64) s += o;
            }
            if (lane == 0) lds_wtot[w] = s;
            __syncthreads();
            int S_later = 0;
#pragma unroll
            for (int w2 = 0; w2 < 4; ++w2) if (w2 > w) S_later += lds_wtot[w2];
            const int S_ab = (s - ts) + S_later;
            if (S_ab < KSEL && S_ab + ts >= KSEL) {
                int cum = S_ab, selb = 0, r1 = 0;
#pragma unroll
                for (int b = 7; b >= 0; --b) {
                    int nx = cum + arr[b];
                    if (cum < KSEL && nx >= KSEL) { selb = 8 * t + b; r1 = KSEL - cum; }
                    cum = nx;
                }
                lds_sel = selb; lds_R1 = r1;
            }
            __syncthreads();
            const int sel = lds_sel, R1 = lds_R1;

            // gather the selected bucket's keys
#pragma unroll
            for (int j = 0; j < VPT; ++j)
#pragma unroll
                for (int c = 0; c < 4; ++c) {
                    unsigned k = kr[j][c];
                    if (kbucket(k) == sel) {
                        int sl = atomicAdd(&lds_cnt, 1);
                        if (sl < LCAP) lkey[sl] = k;
                    }
                }
            __syncthreads();
            const int n = lds_cnt;
            if (n <= LCAP) {
                // propose th: exact R1-th largest of the tiny list
                if (t < n) {
                    unsigned myk = lkey[t];
                    int g = 0, e = 0;
                    for (int i = 0; i < n; ++i) {
                        unsigned k2 = lkey[i];
                        g += (k2 > myk) ? 1 : 0;
                        e += (k2 == myk) ? 1 : 0;
                    }
                    if (g < R1 && g + e >= R1) lds_th = myk;
                }
                __syncthreads();
                th = lds_th;
                // CERTIFY globally: G=#{k>th}, E=#{k==th}; exact top-K predicate
                int ge = 0;
#pragma unroll
                for (int j = 0; j < VPT; ++j)
#pragma unroll
                    for (int c = 0; c < 4; ++c) {
                        unsigned k = kr[j][c];
                        ge += (k > th ? 1 : 0) + (k == th ? (1 << 16) : 0);
                    }
#pragma unroll
                for (int off = 32; off; off >>= 1) ge += __shfl_down(ge, off);
                if (lane == 0) lds_wtot[w] = ge;
                __syncthreads();
                const int GE = lds_wtot[0] + lds_wtot[1] + lds_wtot[2] + lds_wtot[3];
                const int G = GE & 0xFFFF, Eg = GE >> 16;
                if (G < KSEL && G + Eg >= KSEL) { ok = true; Rf = KSEL - G; E = Eg; }
            }
        }

        if (!ok) {
            // proven 4x8-bit key radix select — guaranteed path
            unsigned prefix = 0; int R = KSEL;
            for (int p = 0; p < 4; ++p) {
                const int sh = 24 - 8 * p;
                hist[t] = 0;
                __syncthreads();
#pragma unroll
                for (int j = 0; j < VPT; ++j)
#pragma unroll
                    for (int c = 0; c < 4; ++c) {
                        unsigned k = kr[j][c];
                        if (p == 0 || (k >> (sh + 8)) == (prefix >> (sh + 8)))
                            atomicAdd(&hist[(k >> sh) & 255u], 1);
                    }
                __syncthreads();
                int h = hist[t], s2 = h;
#pragma unroll
                for (int off = 1; off < 64; off <<= 1) {
                    int o = __shfl_down(s2, off);
                    if (lane + off < 64) s2 += o;
                }
                if (lane == 0) lds_wtot[w] = s2;
                __syncthreads();
                int S_later = 0;
#pragma unroll
                for (int w2 = 0; w2 < 4; ++w2) if (w2 > w) S_later += lds_wtot[w2];
                const int S_ab = (s2 - h) + S_later;
                if (S_ab < R && S_ab + h >= R) { lds_sel = t; lds_fR = R - S_ab; lds_fE = h; }
                __syncthreads();
                prefix |= ((unsigned)lds_sel) << sh;
                R = lds_fR;
            }
            th = prefix; Rf = R; E = lds_fE;
        }

        // tie-break (lax.top_k keeps lowest indices) — rare
        unsigned dropm = 0;
        if (E > Rf) {
            unsigned short* tl = (unsigned short*)smem;   // cap 8192 = NCOL, always safe
            __syncthreads();
            if (t == 0) lds_cnt = 0;
            __syncthreads();
#pragma unroll
            for (int j = 0; j < VPT; ++j)
#pragma unroll
                for (int c = 0; c < 4; ++c)
                    if (kr[j][c] == th) {
                        int sl = atomicAdd(&lds_cnt, 1);
                        tl[sl] = (unsigned short)(4 * (t + TPB * j) + c);
                    }
            __syncthreads();
            const int ntie = lds_cnt;
#pragma unroll
            for (int j = 0; j < VPT; ++j)
#pragma unroll
                for (int c = 0; c < 4; ++c)
                    if (kr[j][c] == th) {
                        const int col = 4 * (t + TPB * j) + c;
                        int rank = 0;
                        for (int i = 0; i < ntie; ++i) rank += (tl[i] < col) ? 1 : 0;
                        if (rank >= Rf) dropm |= (1u << (4 * j + c));
                    }
        }

        // write: transmit ORIGINAL x at winners, 0 elsewhere (x re-read, cache-hot)
        f32x4* o4 = (f32x4*)(out + (size_t)row * NCOL);
#pragma unroll
        for (int j = 0; j < VPT; ++j) {
            f32x4 xx = x4[t + TPB * j];
            f32x4 rr;
            rr.x = (kr[j][0] >= th && !((dropm >> (4 * j + 0)) & 1u)) ? xx.x : 0.0f;
            rr.y = (kr[j][1] >= th && !((dropm >> (4 * j + 1)) & 1u)) ? xx.y : 0.0f;
            rr.z = (kr[j][2] >= th && !((dropm >> (4 * j + 2)) & 1u)) ? xx.z : 0.0f;
            rr.w = (kr[j][3] >= th && !((dropm >> (4 * j + 3)) & 1u)) ? xx.w : 0.0f;
            __builtin_nontemporal_store(rr, &o4[t + TPB * j]);
        }

        __syncthreads();   // end-of-row: smem safe to reuse for next row
    }
}

extern "C" void kernel_launch(void* const* d_in, const int* in_sizes, int n_in,
                              void* d_out, int out_size, void* d_ws, size_t ws_size,
                              hipStream_t stream) {
    const float* x = (const float*)d_in[0];        // [4096, 8192] f32
    const float* duty = (const float*)d_in[1];     // [8192] f32
    float* out = (float*)d_out;                    // [4096, 8192] f32
    (void)in_sizes; (void)n_in; (void)out_size; (void)d_ws; (void)ws_size;

    boost_kernel<<<(NCOL + 255) / 256, 256, 0, stream>>>(duty);
    kwinners_kernel<<<NROW / RPB, TPB, 0, stream>>>(x, out);
}

// Round 13
// 70.708 us; speedup vs baseline: 1.0935x; 1.0014x over previous
//
#include <hip/hip_runtime.h>
#include <math.h>

#define NCOL 8192
#define NROW 4096
#define KSEL 819
#define TPB  256
#define VPT  8            // f32x4 per thread = 32 elements
#define LCAP 256          // candidate-list capacity (expected n ~ 1-3)
#define KPIV 0xBF866666u  // f2k(1.05f): survivor pivot in KEY space
#define NBKT 2048

typedef float f32x4 __attribute__((ext_vector_type(4)));

// Per-column boost factors, recomputed every launch (deterministic).
__device__ __align__(16) float g_boost[NCOL];

__global__ void boost_kernel(const float* __restrict__ duty) {
    int i = blockIdx.x * blockDim.x + threadIdx.x;
    if (i < NCOL) {
        // target_density = 819/8192 exactly; boost_strength = 1
        float diff = (0.0999755859375f - duty[i]);
        g_boost[i] = (float)exp((double)diff);   // correctly-rounded f32 exp (matches np)
    }
}

__device__ __forceinline__ unsigned f2k(float f) {
    // monotone float -> uint map (total order)
    unsigned u = __float_as_uint(f);
    return u ^ (0x80000000u | (unsigned)((int)u >> 31));
}

__device__ __forceinline__ int kbucket(unsigned k) {
    // pure-integer monotone bucket of the key; survivors (k>KPIV) -> [0, 2047]
    int b = (int)(k >> 13) - (int)(KPIV >> 13);
    return (b > NBKT - 1) ? (NBKT - 1) : b;
}

__global__ __launch_bounds__(TPB) void kwinners_kernel(const float* __restrict__ x,
                                                       float* __restrict__ out) {
    // smem: [0,8KB) 2048-bucket hist / fallback 256-bin hist / tie list (ushort, 16KB)
    //       [8KB,9KB) lkey[256]
    __shared__ __align__(16) unsigned char smem[16384];
    __shared__ int lds_wtot[4];
    __shared__ int lds_C, lds_cnt, lds_sel, lds_R1, lds_fE, lds_fR;
    __shared__ unsigned lds_th;

    int* hist = (int*)smem;
    unsigned* lkey = (unsigned*)(smem + 8192);

    // ---- de-convoy stagger: per-block phase offset, hash(blockIdx) in {0..7} x 1.5us.
    // Scalar-only (wall_clock64 @100MHz + s_sleep); VGPR cost ~0. Purpose: offset the
    // 8 resident blocks/CU so one block's select phase overlays another's memory phase.
    {
        const unsigned ph = ((unsigned)blockIdx.x * 2654435761u) >> 29;   // 0..7
        if (ph) {
            long long t0 = wall_clock64();
            const long long tgt = (long long)ph * 150;     // 1.5us per step
            while (wall_clock64() - t0 < tgt) __builtin_amdgcn_s_sleep(8);
        }
    }

    const int t = threadIdx.x, row = blockIdx.x, lane = t & 63, w = t >> 6;
    const f32x4* x4 = (const f32x4*)(x + (size_t)row * NCOL);
    const f32x4* b4 = (const f32x4*)g_boost;

    unsigned kr[VPT][4];

    // zero bucket hist + scalars
    {
        int4* h4 = (int4*)hist;
        const int4 z = make_int4(0, 0, 0, 0);
        h4[2 * t] = z; h4[2 * t + 1] = z;
        if (t == 0) { lds_C = 0; lds_cnt = 0; lds_th = 0xFFFFFFFFu; }
    }

    // phase 1: load x + boost, keys -> registers (kept for all later phases)
#pragma unroll
    for (int j = 0; j < VPT; ++j) {
        f32x4 xx = x4[t + TPB * j];
        f32x4 bb = b4[t + TPB * j];
        kr[j][0] = f2k(xx.x * bb.x);
        kr[j][1] = f2k(xx.y * bb.y);
        kr[j][2] = f2k(xx.z * bb.z);
        kr[j][3] = f2k(xx.w * bb.w);
    }
    __syncthreads();

    // survivor count + sparse key-bucket histogram (survivors only)
    int cnt = 0;
#pragma unroll
    for (int j = 0; j < VPT; ++j)
#pragma unroll
        for (int c = 0; c < 4; ++c) {
            unsigned k = kr[j][c];
            if (k > KPIV) { ++cnt; atomicAdd(&hist[kbucket(k)], 1); }
        }
#pragma unroll
    for (int off = 32; off; off >>= 1) cnt += __shfl_down(cnt, off);
    if (lane == 0) atomicAdd(&lds_C, cnt);
    __syncthreads();
    const int C = lds_C;

    unsigned th = 0; int Rf = 0, E = 0; bool ok = false;

    if (C >= KSEL) {
        // one suffix-scan of 2048 buckets (8/thread) -> selected bucket + in-bucket rank
        int arr[8];
        {
            int4 a0 = ((const int4*)hist)[2 * t];
            int4 a1 = ((const int4*)hist)[2 * t + 1];
            arr[0] = a0.x; arr[1] = a0.y; arr[2] = a0.z; arr[3] = a0.w;
            arr[4] = a1.x; arr[5] = a1.y; arr[6] = a1.z; arr[7] = a1.w;
        }
        int ts = arr[0] + arr[1] + arr[2] + arr[3] + arr[4] + arr[5] + arr[6] + arr[7];
        int s = ts;
#pragma unroll
        for (int off = 1; off < 64; off <<= 1) {
            int o = __shfl_down(s, off);
            if (lane + off < 64) s += o;
        }
        if (lane == 0) lds_wtot[w] = s;
        __syncthreads();
        int S_later = 0;
#pragma unroll
        for (int w2 = 0; w2 < 4; ++w2) if (w2 > w) S_later += lds_wtot[w2];
        const int S_ab = (s - ts) + S_later;
        if (S_ab < KSEL && S_ab + ts >= KSEL) {
            int cum = S_ab, selb = 0, r1 = 0;
#pragma unroll
            for (int b = 7; b >= 0; --b) {
                int nx = cum + arr[b];
                if (cum < KSEL && nx >= KSEL) { selb = 8 * t + b; r1 = KSEL - cum; }
                cum = nx;
            }
            lds_sel = selb; lds_R1 = r1;
        }
        __syncthreads();
        const int sel = lds_sel, R1 = lds_R1;

        // gather the selected bucket's keys
#pragma unroll
        for (int j = 0; j < VPT; ++j)
#pragma unroll
            for (int c = 0; c < 4; ++c) {
                unsigned k = kr[j][c];
                if (kbucket(k) == sel) {
                    int sl = atomicAdd(&lds_cnt, 1);
                    if (sl < LCAP) lkey[sl] = k;
                }
            }
        __syncthreads();
        const int n = lds_cnt;
        if (n <= LCAP) {
            // propose th: exact R1-th largest of the tiny list
            if (t < n) {
                unsigned myk = lkey[t];
                int g = 0, e = 0;
                for (int i = 0; i < n; ++i) {
                    unsigned k2 = lkey[i];
                    g += (k2 > myk) ? 1 : 0;
                    e += (k2 == myk) ? 1 : 0;
                }
                if (g < R1 && g + e >= R1) lds_th = myk;
            }
            __syncthreads();
            th = lds_th;
            // CERTIFY globally: G=#{k>th}, E=#{k==th}; exact top-K predicate
            int ge = 0;
#pragma unroll
            for (int j = 0; j < VPT; ++j)
#pragma unroll
                for (int c = 0; c < 4; ++c) {
                    unsigned k = kr[j][c];
                    ge += (k > th ? 1 : 0) + (k == th ? (1 << 16) : 0);
                }
#pragma unroll
            for (int off = 32; off; off >>= 1) ge += __shfl_down(ge, off);
            if (lane == 0) lds_wtot[w] = ge;
            __syncthreads();
            const int GE = lds_wtot[0] + lds_wtot[1] + lds_wtot[2] + lds_wtot[3];
            const int G = GE & 0xFFFF, Eg = GE >> 16;
            if (G < KSEL && G + Eg >= KSEL) { ok = true; Rf = KSEL - G; E = Eg; }
        }
    }

    if (!ok) {
        // proven 4x8-bit key radix select — guaranteed path
        unsigned prefix = 0; int R = KSEL;
        for (int p = 0; p < 4; ++p) {
            const int sh = 24 - 8 * p;
            hist[t] = 0;
            __syncthreads();
#pragma unroll
            for (int j = 0; j < VPT; ++j)
#pragma unroll
                for (int c = 0; c < 4; ++c) {
                    unsigned k = kr[j][c];
                    if (p == 0 || (k >> (sh + 8)) == (prefix >> (sh + 8)))
                        atomicAdd(&hist[(k >> sh) & 255u], 1);
                }
            __syncthreads();
            int h = hist[t], s2 = h;
#pragma unroll
            for (int off = 1; off < 64; off <<= 1) {
                int o = __shfl_down(s2, off);
                if (lane + off < 64) s2 += o;
            }
            if (lane == 0) lds_wtot[w] = s2;
            __syncthreads();
            int S_later = 0;
#pragma unroll
            for (int w2 = 0; w2 < 4; ++w2) if (w2 > w) S_later += lds_wtot[w2];
            const int S_ab = (s2 - h) + S_later;
            if (S_ab < R && S_ab + h >= R) { lds_sel = t; lds_fR = R - S_ab; lds_fE = h; }
            __syncthreads();
            prefix |= ((unsigned)lds_sel) << sh;
            R = lds_fR;
        }
        th = prefix; Rf = R; E = lds_fE;
    }

    // tie-break (lax.top_k keeps lowest indices) — rare
    unsigned dropm = 0;
    if (E > Rf) {
        unsigned short* tl = (unsigned short*)smem;   // cap 8192 = NCOL, always safe
        __syncthreads();
        if (t == 0) lds_cnt = 0;
        __syncthreads();
#pragma unroll
        for (int j = 0; j < VPT; ++j)
#pragma unroll
            for (int c = 0; c < 4; ++c)
                if (kr[j][c] == th) {
                    int sl = atomicAdd(&lds_cnt, 1);
                    tl[sl] = (unsigned short)(4 * (t + TPB * j) + c);
                }
        __syncthreads();
        const int ntie = lds_cnt;
#pragma unroll
        for (int j = 0; j < VPT; ++j)
#pragma unroll
            for (int c = 0; c < 4; ++c)
                if (kr[j][c] == th) {
                    const int col = 4 * (t + TPB * j) + c;
                    int rank = 0;
                    for (int i = 0; i < ntie; ++i) rank += (tl[i] < col) ? 1 : 0;
                    if (rank >= Rf) dropm |= (1u << (4 * j + c));
                }
    }

    // write: transmit ORIGINAL x at winners, 0 elsewhere (x re-read, cache-hot)
    f32x4* o4 = (f32x4*)(out + (size_t)row * NCOL);
#pragma unroll
    for (int j = 0; j < VPT; ++j) {
        f32x4 xx = x4[t + TPB * j];
        f32x4 rr;
        rr.x = (kr[j][0] >= th && !((dropm >> (4 * j + 0)) & 1u)) ? xx.x : 0.0f;
        rr.y = (kr[j][1] >= th && !((dropm >> (4 * j + 1)) & 1u)) ? xx.y : 0.0f;
        rr.z = (kr[j][2] >= th && !((dropm >> (4 * j + 2)) & 1u)) ? xx.z : 0.0f;
        rr.w = (kr[j][3] >= th && !((dropm >> (4 * j + 3)) & 1u)) ? xx.w : 0.0f;
        __builtin_nontemporal_store(rr, &o4[t + TPB * j]);
    }
}

extern "C" void kernel_launch(void* const* d_in, const int* in_sizes, int n_in,
                              void* d_out, int out_size, void* d_ws, size_t ws_size,
                              hipStream_t stream) {
    const float* x = (const float*)d_in[0];        // [4096, 8192] f32
    const float* duty = (const float*)d_in[1];     // [8192] f32
    float* out = (float*)d_out;                    // [4096, 8192] f32
    (void)in_sizes; (void)n_in; (void)out_size; (void)d_ws; (void)ws_size;

    boost_kernel<<<(NCOL + 255) / 256, 256, 0, stream>>>(duty);
    kwinners_kernel<<<NROW, TPB, 0, stream>>>(x, out);
}

// Round 14
// 63.801 us; speedup vs baseline: 1.2119x; 1.1082x over previous
//
#include <hip/hip_runtime.h>
#include <math.h>

#define NCOL 8192
#define NROW 4096
#define KSEL 819
#define TPB  256
#define VPT  8            // f32x4 per thread = 32 elements
#define NBKT 512
#define PIV  1.05f        // survivor pivot: E[C]~1100 >> 819
#define BSCALE 128.0f     // bucket width 1/128 over v in [1.05, 5.05]
#define LCAP 64

typedef float f32x4 __attribute__((ext_vector_type(4)));

// Per-column boost factors, recomputed every launch (deterministic).
__device__ __align__(16) float g_boost[NCOL];

__global__ void boost_kernel(const float* __restrict__ duty) {
    int i = blockIdx.x * blockDim.x + threadIdx.x;
    if (i < NCOL) {
        // target_density = 819/8192 exactly; boost_strength = 1
        float diff = (0.0999755859375f - duty[i]);
        g_boost[i] = (float)exp((double)diff);   // correctly-rounded f32 exp (matches np)
    }
}

__device__ __forceinline__ unsigned f2k(float f) {
    unsigned u = __float_as_uint(f);
    return u ^ (0x80000000u | (unsigned)((int)u >> 31));
}
__device__ __forceinline__ float k2f(unsigned k) {
    unsigned u = (k & 0x80000000u) ? (k ^ 0x80000000u) : ~k;
    return __uint_as_float(u);
}
__device__ __forceinline__ int vbucket(float v) {
    // v > PIV guaranteed at call sites -> (v-PIV) > 0 exactly; trunc = floor; clamp top
    return (int)fminf((v - PIV) * BSCALE, (float)(NBKT - 1));
}

__global__ __launch_bounds__(TPB) void kwinners_kernel(const float* __restrict__ x,
                                                       float* __restrict__ out) {
    __shared__ __align__(16) int hist[NBKT];   // 2 KB; fallback 256 bins / tie list
    __shared__ float list[LCAP];
    __shared__ int wtot[4];
    __shared__ int lds_cnt, lds_sel, lds_R, lds_E;

    const int t = threadIdx.x, lane = t & 63, w = t >> 6;
    const int row = blockIdx.x;
    const f32x4* x4 = (const f32x4*)(x + (size_t)row * NCOL);
    const f32x4* b4 = (const f32x4*)g_boost;
    f32x4* o4 = (f32x4*)(out + (size_t)row * NCOL);
    float* orow = out + (size_t)row * NCOL;

    f32x4 vv[VPT];                             // boosted values — the only row state

    // zero hist (512 ints by 256 threads) + counter
    ((int2*)hist)[t] = make_int2(0, 0);
    if (t == 0) lds_cnt = 0;

    // load x + boost once; vv -> registers
#pragma unroll
    for (int j = 0; j < VPT; ++j) {
        f32x4 xx = x4[t + TPB * j];
        f32x4 bb = b4[t + TPB * j];
        vv[j] = xx * bb;
    }
    __syncthreads();                           // sync1: zeros visible

    // survivor histogram (float buckets)
#pragma unroll
    for (int j = 0; j < VPT; ++j)
#pragma unroll
        for (int c = 0; c < 4; ++c) {
            float v = vv[j][c];
            if (v > PIV) atomicAdd(&hist[vbucket(v)], 1);
        }
    __syncthreads();                           // sync2: hist complete

    // per-wave redundant suffix scan of 512 bins (8/lane); no writeback, no barrier
    int arr[8];
    {
        int4 a0 = ((const int4*)hist)[2 * lane];
        int4 a1 = ((const int4*)hist)[2 * lane + 1];
        arr[0]=a0.x; arr[1]=a0.y; arr[2]=a0.z; arr[3]=a0.w;
        arr[4]=a1.x; arr[5]=a1.y; arr[6]=a1.z; arr[7]=a1.w;
    }
    int ts = arr[0]+arr[1]+arr[2]+arr[3]+arr[4]+arr[5]+arr[6]+arr[7];
    int s = ts;
#pragma unroll
    for (int off = 1; off < 64; off <<= 1) {
        int o = __shfl_down(s, off);
        if (lane + off < 64) s += o;
    }
    const int C = __shfl(s, 0);                // total survivors (wave-uniform)

    float th = 0.0f; int Rf = 0, E = 0;
    bool fb = (C < KSEL);

    if (!fb) {
        const int S_ab = s - ts;               // survivors in buckets above mine
        bool cross = (S_ab < KSEL) && (S_ab + ts >= KSEL);
        int sel_l = 0, r1_l = 0;
        if (cross) {
            int cum = S_ab;
#pragma unroll
            for (int b = 7; b >= 0; --b) {
                int nx = cum + arr[b];
                if (cum < KSEL && nx >= KSEL) { sel_l = 8 * lane + b; r1_l = KSEL - cum; }
                cum = nx;
            }
        }
        unsigned long long m = __ballot(cross);   // exactly one lane per wave
        int src = (int)__ffsll(m) - 1;
        const int sel = __shfl(sel_l, src);
        const int R1  = __shfl(r1_l, src);

        // gather selected bucket's values
#pragma unroll
        for (int j = 0; j < VPT; ++j)
#pragma unroll
            for (int c = 0; c < 4; ++c) {
                float v = vv[j][c];
                if (v > PIV && vbucket(v) == sel) {
                    int sl = atomicAdd(&lds_cnt, 1);
                    if (sl < LCAP) list[sl] = v;
                }
            }
        __syncthreads();                       // sync3: list complete
        const int n = lds_cnt;
        if (n > LCAP || n < 1) fb = true;
        else {
            // per-wave redundant exact rank-select on the tiny list (n <= 64)
            float myv = (lane < n) ? list[lane] : 0.0f;
            int g = 0, e = 0;
            for (int i = 0; i < n; ++i) {
                float vi = __shfl(myv, i);
                g += (vi > myv) ? 1 : 0;
                e += (vi == myv) ? 1 : 0;
            }
            float cand = (lane < n && g < R1 && g + e >= R1) ? myv : 0.0f;
#pragma unroll
            for (int off = 1; off < 64; off <<= 1)
                cand = fmaxf(cand, __shfl_xor(cand, off));
            th = cand;

            // certify + speculative write, fused (x re-read, L2/L3-hot)
            int GE = 0;
#pragma unroll
            for (int j = 0; j < VPT; ++j) {
                f32x4 xx = x4[t + TPB * j];
                f32x4 rr;
#pragma unroll
                for (int c = 0; c < 4; ++c) {
                    float v = vv[j][c];
                    GE += (v > th ? 1 : 0) + (v == th ? (1 << 16) : 0);
                    rr[c] = (v >= th) ? xx[c] : 0.0f;
                }
                __builtin_nontemporal_store(rr, &o4[t + TPB * j]);
            }
#pragma unroll
            for (int off = 1; off < 64; off <<= 1) GE += __shfl_xor(GE, off);
            if (lane == 0) wtot[w] = GE;
            __syncthreads();                   // sync4: combine waves
            const int GEt = wtot[0] + wtot[1] + wtot[2] + wtot[3];
            const int G = GEt & 0xFFFF, Eg = GEt >> 16;
            if (G < KSEL && G + Eg >= KSEL) { Rf = KSEL - G; E = Eg; }
            else fb = true;                    // certification failed
        }
    }

    if (fb) {   // guaranteed 4x8-bit key radix (rare), float recount, rewrite row
        asm volatile("s_waitcnt vmcnt(0)" ::: "memory");
        __syncthreads();
        unsigned prefix = 0; int R = KSEL;
        for (int p = 0; p < 4; ++p) {
            const int sh = 24 - 8 * p;
            if (t < 256) hist[t] = 0;
            __syncthreads();
#pragma unroll
            for (int j = 0; j < VPT; ++j)
#pragma unroll
                for (int c = 0; c < 4; ++c) {
                    unsigned k = f2k(vv[j][c]);
                    if (p == 0 || (k >> (sh + 8)) == (prefix >> (sh + 8)))
                        atomicAdd(&hist[(k >> sh) & 255u], 1);
                }
            __syncthreads();
            int h = (t < 256) ? hist[t] : 0, s2 = h;
#pragma unroll
            for (int off = 1; off < 64; off <<= 1) {
                int o = __shfl_down(s2, off);
                if (lane + off < 64) s2 += o;
            }
            if (lane == 0) wtot[w] = s2;
            __syncthreads();
            int S_later = 0;
#pragma unroll
            for (int w2 = 0; w2 < 4; ++w2) if (w2 > w) S_later += wtot[w2];
            const int S_ab2 = (s2 - h) + S_later;
            if (S_ab2 < R && S_ab2 + h >= R) { lds_sel = t; lds_R = R - S_ab2; }
            __syncthreads();
            prefix |= ((unsigned)lds_sel) << sh;
            R = lds_R;
        }
        th = k2f(prefix);
        // float-space recount (G,E) + full rewrite
        int GE = 0;
#pragma unroll
        for (int j = 0; j < VPT; ++j) {
            f32x4 xx = x4[t + TPB * j];
            f32x4 rr;
#pragma unroll
            for (int c = 0; c < 4; ++c) {
                float v = vv[j][c];
                GE += (v > th ? 1 : 0) + (v == th ? (1 << 16) : 0);
                rr[c] = (v >= th) ? xx[c] : 0.0f;
            }
            o4[t + TPB * j] = rr;
        }
#pragma unroll
        for (int off = 1; off < 64; off <<= 1) GE += __shfl_xor(GE, off);
        if (lane == 0) wtot[w] = GE;
        __syncthreads();
        const int GEt = wtot[0] + wtot[1] + wtot[2] + wtot[3];
        const int G = GEt & 0xFFFF;
        Rf = KSEL - G; E = GEt >> 16;
    }

    if (E > Rf) {   // tie demotion patch (lax.top_k keeps lowest columns) — rare
        asm volatile("s_waitcnt vmcnt(0)" ::: "memory");
        __syncthreads();
        unsigned short* tl = (unsigned short*)hist;   // 2KB -> cap 1024 cols
        if (t == 0) lds_cnt = 0;
        __syncthreads();
#pragma unroll
        for (int j = 0; j < VPT; ++j)
#pragma unroll
            for (int c = 0; c < 4; ++c)
                if (vv[j][c] == th) {
                    int sl = atomicAdd(&lds_cnt, 1);
                    if (sl < 1024) tl[sl] = (unsigned short)(4 * (t + TPB * j) + c);
                }
        __syncthreads();
        const int ntie = lds_cnt;
        if (ntie <= 1024) {
#pragma unroll
            for (int j = 0; j < VPT; ++j)
#pragma unroll
                for (int c = 0; c < 4; ++c)
                    if (vv[j][c] == th) {
                        const int col = 4 * (t + TPB * j) + c;
                        int rk = 0;
                        for (int i = 0; i < ntie; ++i) rk += (tl[i] < col) ? 1 : 0;
                        if (rk >= Rf) orow[col] = 0.0f;
                    }
        } else if (t == 0) {   // >1024 identical values: never on real data, but correct
            int seen = 0;
            for (int col = 0; col < NCOL; ++col) {
                float v = x[(size_t)row * NCOL + col] * g_boost[col];  // == vv bitwise
                if (v == th) { if (seen >= Rf) orow[col] = 0.0f; ++seen; }
            }
        }
    }
}

extern "C" void kernel_launch(void* const* d_in, const int* in_sizes, int n_in,
                              void* d_out, int out_size, void* d_ws, size_t ws_size,
                              hipStream_t stream) {
    const float* x = (const float*)d_in[0];        // [4096, 8192] f32
    const float* duty = (const float*)d_in[1];     // [8192] f32
    float* out = (float*)d_out;                    // [4096, 8192] f32
    (void)in_sizes; (void)n_in; (void)out_size; (void)d_ws; (void)ws_size;

    boost_kernel<<<(NCOL + 255) / 256, 256, 0, stream>>>(duty);
    kwinners_kernel<<<NROW, TPB, 0, stream>>>(x, out);
}